// Round 1
// baseline (1047.460 us; speedup 1.0000x reference)
//
#include <hip/hip_runtime.h>

// ContinuousConv: N=200000, M=100000, CIN=32, COUT=64, K=32, KS=3
// Inputs (dict order):
// 0 inp_features [N,32] f32, 1 inp_positions [N,3] f32, 2 out_positions [M,3] f32,
// 3 extents [1] f32, 4 inp_importance [N] f32, 5 neighbors_index [M,32] i32,
// 6 kernel [3,3,3,32,64] f32 (flat 27*32*64=55296), 7 bias [64] f32
// Output: [M,64] f32

constexpr int MPTS = 100000;
constexpr int MT   = 16;     // points per block
constexpr int NCHUNK = 27;   // filter voxels

__global__ __launch_bounds__(256, 2)
void cconv_kernel(const float* __restrict__ feats,
                  const float* __restrict__ inpos,
                  const float* __restrict__ outpos,
                  const float* __restrict__ extents,
                  const float* __restrict__ importance,
                  const int*   __restrict__ nbrs,
                  const float* __restrict__ kern,
                  const float* __restrict__ bias,
                  float* __restrict__ out)
{
    __shared__ float acc_s[MT][27 * 32];   // 55296 B
    __shared__ float kk_t[64][34];         // transposed filter chunk, 8704 B
    __shared__ float nrm_s[MT];

    const int tid  = threadIdx.x;
    const int wv   = tid >> 6;    // wave 0..3
    const int lane = tid & 63;
    const int half = lane >> 5;   // neighbor parity
    const int ch   = lane & 31;   // input channel

    const float inv_r = 2.0f / extents[0];   // 1/(0.5*extents)

    // ---------------- Phase 1: accumulate acc[27][CIN] per point ----------------
    for (int p = 0; p < 4; ++p) {
        const int mt = wv * 4 + p;
        const int m  = blockIdx.x * MT + mt;
        const float ox = outpos[3 * m + 0];
        const float oy = outpos[3 * m + 1];
        const float oz = outpos[3 * m + 2];

        float acc[27];
#pragma unroll
        for (int v = 0; v < 27; ++v) acc[v] = 0.0f;
        float norm = 0.0f;

        for (int t = 0; t < 16; ++t) {
            const int nb = nbrs[m * 32 + 2 * t + half];
            const float rx = (inpos[3 * nb + 0] - ox) * inv_r;
            const float ry = (inpos[3 * nb + 1] - oy) * inv_r;
            const float rz = (inpos[3 * nb + 2] - oz) * inv_r;
            const float d2   = rx * rx + ry * ry + rz * rz;
            const float dist = sqrtf(d2);
            float imp = importance[nb];
            imp = (dist <= 1.0f) ? imp : 0.0f;

            const float ax = fabsf(rx), ay = fabsf(ry), az = fabsf(rz);
            const float linf  = fmaxf(ax, fmaxf(ay, az));
            const float scale = (linf > 1e-8f) ? (dist / linf) : 0.0f;

            // ball->cube, then map [-1,1] -> [0,2] with clamp
            const float cx = fminf(fmaxf(rx * scale + 1.0f, 0.0f), 2.0f);
            const float cy = fminf(fmaxf(ry * scale + 1.0f, 0.0f), 2.0f);
            const float cz = fminf(fmaxf(rz * scale + 1.0f, 0.0f), 2.0f);

            const float wx0 = fmaxf(0.0f, 1.0f - cx);
            const float wx1 = 1.0f - fabsf(cx - 1.0f);
            const float wx2 = fmaxf(0.0f, cx - 1.0f);
            const float wy0 = fmaxf(0.0f, 1.0f - cy);
            const float wy1 = 1.0f - fabsf(cy - 1.0f);
            const float wy2 = fmaxf(0.0f, cy - 1.0f);
            const float wz0 = fmaxf(0.0f, 1.0f - cz);
            const float wz1 = 1.0f - fabsf(cz - 1.0f);
            const float wz2 = fmaxf(0.0f, cz - 1.0f);

            norm += imp;
            const float f  = feats[nb * 32 + ch] * imp;
            const float g0 = f * wz0, g1 = f * wz1, g2 = f * wz2;

            const float wxy[9] = { wx0 * wy0, wx0 * wy1, wx0 * wy2,
                                   wx1 * wy0, wx1 * wy1, wx1 * wy2,
                                   wx2 * wy0, wx2 * wy1, wx2 * wy2 };
#pragma unroll
            for (int ab = 0; ab < 9; ++ab) {
                acc[ab * 3 + 0] += wxy[ab] * g0;
                acc[ab * 3 + 1] += wxy[ab] * g1;
                acc[ab * 3 + 2] += wxy[ab] * g2;
            }
        }

        // combine the two neighbor-parity halves
#pragma unroll
        for (int v = 0; v < 27; ++v) acc[v] += __shfl_xor(acc[v], 32);
        norm += __shfl_xor(norm, 32);

        if (half == 0) {
#pragma unroll
            for (int v = 0; v < 27; ++v) acc_s[mt][v * 32 + ch] = acc[v];
            if (ch == 0)
                nrm_s[mt] = (norm > 0.0f) ? (1.0f / fmaxf(norm, 1e-12f)) : 0.0f;
        }
    }
    __syncthreads();

    // ---------------- Phase 2: out[mt][o] = acc[mt][:] . W[:][o] ----------------
    const int q  = tid & 31;
    const int g  = tid >> 5;      // 0..7
    const int o0 = q, o1 = q + 32;
    const int mA = g, mB = g + 8;

    float s00 = 0.f, s01 = 0.f, s10 = 0.f, s11 = 0.f;

    for (int c = 0; c < NCHUNK; ++c) {
        // stage filter chunk c (32 x 64) transposed into LDS
        {
            const float4* src = (const float4*)(kern + c * 2048 + tid * 8);
            const float4 v0 = src[0];
            const float4 v1 = src[1];
            const int i  = tid >> 3;
            const int ob = (tid & 7) * 8;
            kk_t[ob + 0][i] = v0.x; kk_t[ob + 1][i] = v0.y;
            kk_t[ob + 2][i] = v0.z; kk_t[ob + 3][i] = v0.w;
            kk_t[ob + 4][i] = v1.x; kk_t[ob + 5][i] = v1.y;
            kk_t[ob + 6][i] = v1.z; kk_t[ob + 7][i] = v1.w;
        }
        __syncthreads();

#pragma unroll
        for (int i4 = 0; i4 < 8; ++i4) {
            const float4 aa = *(const float4*)&acc_s[mA][c * 32 + i4 * 4];
            const float4 ab = *(const float4*)&acc_s[mB][c * 32 + i4 * 4];
            const float2 k0a = *(const float2*)&kk_t[o0][i4 * 4];
            const float2 k0b = *(const float2*)&kk_t[o0][i4 * 4 + 2];
            const float2 k1a = *(const float2*)&kk_t[o1][i4 * 4];
            const float2 k1b = *(const float2*)&kk_t[o1][i4 * 4 + 2];
            s00 += aa.x * k0a.x + aa.y * k0a.y + aa.z * k0b.x + aa.w * k0b.y;
            s01 += aa.x * k1a.x + aa.y * k1a.y + aa.z * k1b.x + aa.w * k1b.y;
            s10 += ab.x * k0a.x + ab.y * k0a.y + ab.z * k0b.x + ab.w * k0b.y;
            s11 += ab.x * k1a.x + ab.y * k1a.y + ab.z * k1b.x + ab.w * k1b.y;
        }
        __syncthreads();
    }

    const float nA = nrm_s[mA];
    const float nB = nrm_s[mB];
    const float b0 = bias[o0];
    const float b1 = bias[o1];
    const int mgA = blockIdx.x * MT + mA;
    const int mgB = blockIdx.x * MT + mB;
    out[mgA * 64 + o0] = s00 * nA + b0;
    out[mgA * 64 + o1] = s01 * nA + b1;
    out[mgB * 64 + o0] = s10 * nB + b0;
    out[mgB * 64 + o1] = s11 * nB + b1;
}

extern "C" void kernel_launch(void* const* d_in, const int* in_sizes, int n_in,
                              void* d_out, int out_size, void* d_ws, size_t ws_size,
                              hipStream_t stream) {
    (void)in_sizes; (void)n_in; (void)out_size; (void)d_ws; (void)ws_size;
    const float* feats      = (const float*)d_in[0];
    const float* inpos      = (const float*)d_in[1];
    const float* outpos     = (const float*)d_in[2];
    const float* extents    = (const float*)d_in[3];
    const float* importance = (const float*)d_in[4];
    const int*   nbrs       = (const int*)d_in[5];
    const float* kern       = (const float*)d_in[6];
    const float* bias       = (const float*)d_in[7];
    float* outp = (float*)d_out;

    dim3 grid(MPTS / MT);   // 6250
    dim3 block(256);
    hipLaunchKernelGGL(cconv_kernel, grid, block, 0, stream,
                       feats, inpos, outpos, extents, importance,
                       nbrs, kern, bias, outp);
}

// Round 2
// 277.585 us; speedup vs baseline: 3.7735x; 3.7735x over previous
//
#include <hip/hip_runtime.h>

// ContinuousConv: N=200000, M=100000, CIN=32, COUT=64, K=32, KS=3
// MFMA design:
//  phase 0: per-(pt,k) thread computes 27 trilinear weights (x imp), bf16 -> LDS w_s[pt][v][k]
//  phase 1: per point, acc[28v x 32ch] = w[28v x 32k] . f[32k x 32ch] via 4x mfma_16x16x32_bf16
//           (A from LDS b128; B gathered straight from global feats; D -> bf16 LDS acc_s, kk = ch*28+v)
//  phase 2: out[8pt x 64o] = acc[8 x 896] . Wfrag via 2x28 mfma per wave; Wfrag pre-transposed
//           to exact fragment order in d_ws by wprep_kernel (zero at v==27 pad slots).

typedef __attribute__((ext_vector_type(8))) __bf16 bf16x8;
typedef __attribute__((ext_vector_type(4))) __bf16 bf16x4;
typedef __attribute__((ext_vector_type(4))) float f32x4;

constexpr int MPTS = 100000;
constexpr int MB   = 8;                    // points per block
constexpr int NBLK = MPTS / MB;            // 12500

// LDS layout (bytes), single buffer:
//  w_s  : [8 pt][28 v][40 k-slots] u16 ; strides pt=2240, v=80, k=2 ; 17920 B
//         (phase-1 A-frag reads v up to 31 run past a pt's 28 rows -> finite garbage,
//          feeds only discarded D rows 28..31)
//  acc_s: [8 pt][904 kk] u16 (896 used, kk = ch*28+v, +8 pad for bank spread) ; 14464 B
//  nrm  : 8 f32
constexpr int W_PT    = 2240;
constexpr int W_V     = 80;
constexpr int ACC_OFF = 17920;
constexpr int ACC_PT  = 1808;
constexpr int NRM_OFF = ACC_OFF + MB * ACC_PT;   // 32384
constexpr int LDS_BYTES = NRM_OFF + 32;          // 32416 -> ~5 blocks/CU

// ---- pre-kernel: kernel[27][32][64] f32 -> fragment-ordered bf16 in d_ws ----
// Wfrag[nt][ks][lane][j] = W_bf16[ o = nt*16+(lane&15) ][ kk = ks*32 + (lane>>4)*8 + j ]
// with kk = ch*28 + v ; zero at pad v==27.  Size: 4*28*64*8 u16 = 114688 B.
__global__ void wprep_kernel(const float* __restrict__ kern, __bf16* __restrict__ wsb) {
    const int tid = blockIdx.x * 256 + threadIdx.x;
    if (tid >= 4 * 28 * 64 * 8) return;
    const int j  = tid & 7;
    const int l  = (tid >> 3) & 63;
    const int s  = tid >> 9;             // 0..111
    const int ks = s % 28;
    const int nt = s / 28;
    const int kk = ks * 32 + ((l >> 4) << 3) + j;
    const int ch = kk / 28;
    const int v  = kk - ch * 28;
    const int o  = nt * 16 + (l & 15);
    const float val = (v < 27) ? kern[v * 2048 + ch * 64 + o] : 0.0f;
    wsb[tid] = (__bf16)val;
}

__global__ __launch_bounds__(128, 2)
void cconv_kernel(const float* __restrict__ feats,
                  const float* __restrict__ inpos,
                  const float* __restrict__ outpos,
                  const float* __restrict__ extents,
                  const float* __restrict__ importance,
                  const int*   __restrict__ nbrs,
                  const __bf16* __restrict__ wfrag,
                  const float* __restrict__ bias,
                  float* __restrict__ out)
{
    __shared__ __align__(16) unsigned char smem[LDS_BYTES];

    const int tid = threadIdx.x;
    const int blk = blockIdx.x;
    float* nrm = (float*)(smem + NRM_OFF);

    const float inv_r = 2.0f / extents[0];

    // ---------------- phase 0: weights ----------------
#pragma unroll
    for (int i = 0; i < 2; ++i) {
        const int p  = tid + 128 * i;
        const int pt = p >> 5;
        const int k  = p & 31;
        const int m  = blk * MB + pt;
        const int nb = nbrs[m * 32 + k];

        const float ox = outpos[3 * m + 0];
        const float oy = outpos[3 * m + 1];
        const float oz = outpos[3 * m + 2];
        const float rx = (inpos[3 * nb + 0] - ox) * inv_r;
        const float ry = (inpos[3 * nb + 1] - oy) * inv_r;
        const float rz = (inpos[3 * nb + 2] - oz) * inv_r;

        const float dist = sqrtf(rx * rx + ry * ry + rz * rz);
        float imp = importance[nb];
        imp = (dist <= 1.0f) ? imp : 0.0f;

        const float linf  = fmaxf(fabsf(rx), fmaxf(fabsf(ry), fabsf(rz)));
        const float scale = (linf > 1e-8f) ? (dist / linf) : 0.0f;
        const float cx = fminf(fmaxf(rx * scale + 1.0f, 0.0f), 2.0f);
        const float cy = fminf(fmaxf(ry * scale + 1.0f, 0.0f), 2.0f);
        const float cz = fminf(fmaxf(rz * scale + 1.0f, 0.0f), 2.0f);

        float wx[3], wy[3], wz[3];
        wx[0] = fmaxf(0.f, 1.f - cx) * imp;          // importance folded into x-axis
        wx[1] = (1.f - fabsf(cx - 1.f)) * imp;
        wx[2] = fmaxf(0.f, cx - 1.f) * imp;
        wy[0] = fmaxf(0.f, 1.f - cy);
        wy[1] = 1.f - fabsf(cy - 1.f);
        wy[2] = fmaxf(0.f, cy - 1.f);
        wz[0] = fmaxf(0.f, 1.f - cz);
        wz[1] = 1.f - fabsf(cz - 1.f);
        wz[2] = fmaxf(0.f, cz - 1.f);

        unsigned char* wrow = smem + pt * W_PT + k * 2;
#pragma unroll
        for (int a = 0; a < 3; ++a)
#pragma unroll
            for (int b = 0; b < 3; ++b) {
                const float wab = wx[a] * wy[b];
#pragma unroll
                for (int c = 0; c < 3; ++c) {
                    const int v = a * 9 + b * 3 + c;
                    *(__bf16*)(wrow + v * W_V) = (__bf16)(wab * wz[c]);
                }
            }
        *(__bf16*)(wrow + 27 * W_V) = (__bf16)0.0f;   // pad voxel row -> zero

        float s = imp;
        s += __shfl_xor(s, 1);
        s += __shfl_xor(s, 2);
        s += __shfl_xor(s, 4);
        s += __shfl_xor(s, 8);
        s += __shfl_xor(s, 16);
        if (k == 0) nrm[pt] = (s > 0.f) ? (1.f / fmaxf(s, 1e-12f)) : 0.f;
    }
    __syncthreads();

    // ---------------- phase 1: acc = w . f ----------------
    const int wv   = tid >> 6;       // wave 0/1
    const int lane = tid & 63;
    const int grp  = lane >> 4;      // k-group
    const int lr   = lane & 15;
    const int k0   = grp * 8;

#pragma unroll
    for (int q = 0; q < 4; ++q) {
        const int pt = wv * 4 + q;
        const int m  = blk * MB + pt;

        const int4 nA = *(const int4*)(nbrs + m * 32 + k0);
        const int4 nB = *(const int4*)(nbrs + m * 32 + k0 + 4);

        const bf16x8 a0 = *(const bf16x8*)(smem + pt * W_PT + lr * W_V + k0 * 2);
        const bf16x8 a1 = *(const bf16x8*)(smem + pt * W_PT + (16 + lr) * W_V + k0 * 2);

        bf16x8 b0, b1;
        {
            const int n0 = nA.x, n1 = nA.y, n2 = nA.z, n3 = nA.w;
            const int n4 = nB.x, n5 = nB.y, n6 = nB.z, n7 = nB.w;
            b0[0] = (__bf16)feats[n0 * 32 + lr];      b1[0] = (__bf16)feats[n0 * 32 + 16 + lr];
            b0[1] = (__bf16)feats[n1 * 32 + lr];      b1[1] = (__bf16)feats[n1 * 32 + 16 + lr];
            b0[2] = (__bf16)feats[n2 * 32 + lr];      b1[2] = (__bf16)feats[n2 * 32 + 16 + lr];
            b0[3] = (__bf16)feats[n3 * 32 + lr];      b1[3] = (__bf16)feats[n3 * 32 + 16 + lr];
            b0[4] = (__bf16)feats[n4 * 32 + lr];      b1[4] = (__bf16)feats[n4 * 32 + 16 + lr];
            b0[5] = (__bf16)feats[n5 * 32 + lr];      b1[5] = (__bf16)feats[n5 * 32 + 16 + lr];
            b0[6] = (__bf16)feats[n6 * 32 + lr];      b1[6] = (__bf16)feats[n6 * 32 + 16 + lr];
            b0[7] = (__bf16)feats[n7 * 32 + lr];      b1[7] = (__bf16)feats[n7 * 32 + 16 + lr];
        }

        f32x4 d00 = {0.f, 0.f, 0.f, 0.f}, d01 = {0.f, 0.f, 0.f, 0.f};
        f32x4 d10 = {0.f, 0.f, 0.f, 0.f}, d11 = {0.f, 0.f, 0.f, 0.f};
        d00 = __builtin_amdgcn_mfma_f32_16x16x32_bf16(a0, b0, d00, 0, 0, 0);
        d01 = __builtin_amdgcn_mfma_f32_16x16x32_bf16(a0, b1, d01, 0, 0, 0);
        d10 = __builtin_amdgcn_mfma_f32_16x16x32_bf16(a1, b0, d10, 0, 0, 0);
        d11 = __builtin_amdgcn_mfma_f32_16x16x32_bf16(a1, b1, d11, 0, 0, 0);

        // D rows = voxels, cols = channels ; store kk = ch*28 + v as bf16
        const int vb0 = grp * 4;
        const int vb1 = 16 + grp * 4;
        {
            bf16x4 t;
            t[0] = (__bf16)d00[0]; t[1] = (__bf16)d00[1]; t[2] = (__bf16)d00[2]; t[3] = (__bf16)d00[3];
            *(bf16x4*)(smem + ACC_OFF + pt * ACC_PT + lr * 56 + vb0 * 2) = t;
            t[0] = (__bf16)d01[0]; t[1] = (__bf16)d01[1]; t[2] = (__bf16)d01[2]; t[3] = (__bf16)d01[3];
            *(bf16x4*)(smem + ACC_OFF + pt * ACC_PT + (16 + lr) * 56 + vb0 * 2) = t;
            if (vb1 < 28) {
                t[0] = (__bf16)d10[0]; t[1] = (__bf16)d10[1]; t[2] = (__bf16)d10[2]; t[3] = (__bf16)d10[3];
                *(bf16x4*)(smem + ACC_OFF + pt * ACC_PT + lr * 56 + vb1 * 2) = t;
                t[0] = (__bf16)d11[0]; t[1] = (__bf16)d11[1]; t[2] = (__bf16)d11[2]; t[3] = (__bf16)d11[3];
                *(bf16x4*)(smem + ACC_OFF + pt * ACC_PT + (16 + lr) * 56 + vb1 * 2) = t;
            }
        }
    }
    __syncthreads();

    // ---------------- phase 2: out = acc . W ----------------
    const int nt0 = wv * 2, nt1 = wv * 2 + 1;
    f32x4 e0 = {0.f, 0.f, 0.f, 0.f}, e1 = {0.f, 0.f, 0.f, 0.f};
    const bf16x8* wb = (const bf16x8*)wfrag;
    const unsigned char* abase = smem + ACC_OFF + (lr & 7) * ACC_PT + grp * 16;

#pragma unroll 4
    for (int ks = 0; ks < 28; ++ks) {
        const bf16x8 a  = *(const bf16x8*)(abase + ks * 64);
        const bf16x8 w0 = wb[(nt0 * 28 + ks) * 64 + lane];
        const bf16x8 w1 = wb[(nt1 * 28 + ks) * 64 + lane];
        e0 = __builtin_amdgcn_mfma_f32_16x16x32_bf16(a, w0, e0, 0, 0, 0);
        e1 = __builtin_amdgcn_mfma_f32_16x16x32_bf16(a, w1, e1, 0, 0, 0);
    }

    const int o0 = nt0 * 16 + lr;
    const int o1 = nt1 * 16 + lr;
    const float bb0 = bias[o0];
    const float bb1 = bias[o1];
    if (grp < 2) {
#pragma unroll
        for (int r = 0; r < 4; ++r) {
            const int pt = grp * 4 + r;      // D row = pt (rows 8..15 are dups, skipped)
            const float nv = nrm[pt];
            const int mg = blk * MB + pt;
            out[mg * 64 + o0] = e0[r] * nv + bb0;
            out[mg * 64 + o1] = e1[r] * nv + bb1;
        }
    }
}

extern "C" void kernel_launch(void* const* d_in, const int* in_sizes, int n_in,
                              void* d_out, int out_size, void* d_ws, size_t ws_size,
                              hipStream_t stream) {
    (void)in_sizes; (void)n_in; (void)out_size; (void)ws_size;
    const float* feats      = (const float*)d_in[0];
    const float* inpos      = (const float*)d_in[1];
    const float* outpos     = (const float*)d_in[2];
    const float* extents    = (const float*)d_in[3];
    const float* importance = (const float*)d_in[4];
    const int*   nbrs       = (const int*)d_in[5];
    const float* kern       = (const float*)d_in[6];
    const float* bias       = (const float*)d_in[7];
    float* outp   = (float*)d_out;
    __bf16* wsb   = (__bf16*)d_ws;          // needs 114688 B of scratch

    hipLaunchKernelGGL(wprep_kernel, dim3(224), dim3(256), 0, stream, kern, wsb);
    hipLaunchKernelGGL(cconv_kernel, dim3(NBLK), dim3(128), 0, stream,
                       feats, inpos, outpos, extents, importance,
                       nbrs, wsb, bias, outp);
}

// Round 3
// 210.805 us; speedup vs baseline: 4.9689x; 1.3168x over previous
//
#include <hip/hip_runtime.h>

// ContinuousConv: N=200000, M=100000, CIN=32, COUT=64, K=32, KS=3
// Round 3: LDS aliasing (w overwritten by acc per-pt), no phase0->1 barrier,
// k-paired phase-0 writes, software-pipelined gathers, prefetched phase-2 W.

typedef __attribute__((ext_vector_type(8))) __bf16 bf16x8;
typedef __attribute__((ext_vector_type(4))) __bf16 bf16x4;
typedef __attribute__((ext_vector_type(4))) float f32x4;

constexpr int MPTS = 100000;
constexpr int MB   = 8;                    // points per block
constexpr int NBLK = MPTS / MB;            // 12500

// Per-pt LDS region (PT_STRIDE bytes), reused in time:
//   phase 0/1 read : w[v=0..27][k-slot 0..39] bf16, row stride 80 B (2240 B)
//   phase 1 write  : acc[kk = ch*28+v] bf16, 1792 B (overwrites w after reads)
// nrm[8] f32 after the 8 regions; + tail pad for harmless garbage-row reads.
constexpr int PT_STRIDE = 2240;
constexpr int W_V       = 80;              // bytes per voxel row (40 k-slots)
constexpr int NRM_OFF   = MB * PT_STRIDE;  // 17920
constexpr int LDS_BYTES = NRM_OFF + 32 + 304;   // 18256

// ---- pre-kernel: kernel[27][32][64] f32 -> fragment-ordered bf16 in d_ws ----
// Wfrag[nt][ks][lane][j] = W_bf16[ o = nt*16+(lane&15) ][ kk = ks*32 + (lane>>4)*8 + j ]
// with kk = ch*28 + v ; zero at pad v==27.  Size: 4*28*64*8 u16 = 114688 B.
__global__ void wprep_kernel(const float* __restrict__ kern, __bf16* __restrict__ wsb) {
    const int tid = blockIdx.x * 256 + threadIdx.x;
    if (tid >= 4 * 28 * 64 * 8) return;
    const int j  = tid & 7;
    const int l  = (tid >> 3) & 63;
    const int s  = tid >> 9;             // 0..111
    const int ks = s % 28;
    const int nt = s / 28;
    const int kk = ks * 32 + ((l >> 4) << 3) + j;
    const int ch = kk / 28;
    const int v  = kk - ch * 28;
    const int o  = nt * 16 + (l & 15);
    const float val = (v < 27) ? kern[v * 2048 + ch * 64 + o] : 0.0f;
    wsb[tid] = (__bf16)val;
}

// stage 16 feature floats for one point's 8 neighbors (2 channel halves)
#define STAGE(f, A, B) do {                                              \
    f[0]  = feats[(size_t)(A).x * 32 + lr];                              \
    f[1]  = feats[(size_t)(A).y * 32 + lr];                              \
    f[2]  = feats[(size_t)(A).z * 32 + lr];                              \
    f[3]  = feats[(size_t)(A).w * 32 + lr];                              \
    f[4]  = feats[(size_t)(B).x * 32 + lr];                              \
    f[5]  = feats[(size_t)(B).y * 32 + lr];                              \
    f[6]  = feats[(size_t)(B).z * 32 + lr];                              \
    f[7]  = feats[(size_t)(B).w * 32 + lr];                              \
    f[8]  = feats[(size_t)(A).x * 32 + 16 + lr];                         \
    f[9]  = feats[(size_t)(A).y * 32 + 16 + lr];                         \
    f[10] = feats[(size_t)(A).z * 32 + 16 + lr];                         \
    f[11] = feats[(size_t)(A).w * 32 + 16 + lr];                         \
    f[12] = feats[(size_t)(B).x * 32 + 16 + lr];                         \
    f[13] = feats[(size_t)(B).y * 32 + 16 + lr];                         \
    f[14] = feats[(size_t)(B).z * 32 + 16 + lr];                         \
    f[15] = feats[(size_t)(B).w * 32 + 16 + lr];                         \
} while (0)

// one point's phase-1: convert fragment, 4 MFMAs, store acc over the w region
#define COMPUTE(qq, f) do {                                              \
    unsigned char* pbase = smem + (wv * 4 + (qq)) * PT_STRIDE;           \
    bf16x8 b0, b1;                                                       \
    b0[0] = (__bf16)f[0];  b0[1] = (__bf16)f[1];                         \
    b0[2] = (__bf16)f[2];  b0[3] = (__bf16)f[3];                         \
    b0[4] = (__bf16)f[4];  b0[5] = (__bf16)f[5];                         \
    b0[6] = (__bf16)f[6];  b0[7] = (__bf16)f[7];                         \
    b1[0] = (__bf16)f[8];  b1[1] = (__bf16)f[9];                         \
    b1[2] = (__bf16)f[10]; b1[3] = (__bf16)f[11];                        \
    b1[4] = (__bf16)f[12]; b1[5] = (__bf16)f[13];                        \
    b1[6] = (__bf16)f[14]; b1[7] = (__bf16)f[15];                        \
    const bf16x8 a0 = *(const bf16x8*)(pbase + lr * W_V + k0 * 2);       \
    const bf16x8 a1 = *(const bf16x8*)(pbase + (16 + lr) * W_V + k0 * 2);\
    f32x4 d00 = {0.f,0.f,0.f,0.f}, d01 = {0.f,0.f,0.f,0.f};              \
    f32x4 d10 = {0.f,0.f,0.f,0.f}, d11 = {0.f,0.f,0.f,0.f};              \
    d00 = __builtin_amdgcn_mfma_f32_16x16x32_bf16(a0, b0, d00, 0, 0, 0); \
    d01 = __builtin_amdgcn_mfma_f32_16x16x32_bf16(a0, b1, d01, 0, 0, 0); \
    d10 = __builtin_amdgcn_mfma_f32_16x16x32_bf16(a1, b0, d10, 0, 0, 0); \
    d11 = __builtin_amdgcn_mfma_f32_16x16x32_bf16(a1, b1, d11, 0, 0, 0); \
    const int vb0 = grp * 4, vb1 = 16 + grp * 4;                         \
    bf16x4 t0, t1;                                                       \
    t0[0] = (__bf16)d00[0]; t0[1] = (__bf16)d00[1];                      \
    t0[2] = (__bf16)d00[2]; t0[3] = (__bf16)d00[3];                      \
    *(bf16x4*)(pbase + (lr * 28 + vb0) * 2) = t0;                        \
    t1[0] = (__bf16)d01[0]; t1[1] = (__bf16)d01[1];                      \
    t1[2] = (__bf16)d01[2]; t1[3] = (__bf16)d01[3];                      \
    *(bf16x4*)(pbase + ((16 + lr) * 28 + vb0) * 2) = t1;                 \
    if (vb1 < 28) {                                                      \
        bf16x4 t2, t3;                                                   \
        t2[0] = (__bf16)d10[0]; t2[1] = (__bf16)d10[1];                  \
        t2[2] = (__bf16)d10[2]; t2[3] = (__bf16)d10[3];                  \
        *(bf16x4*)(pbase + (lr * 28 + vb1) * 2) = t2;                    \
        t3[0] = (__bf16)d11[0]; t3[1] = (__bf16)d11[1];                  \
        t3[2] = (__bf16)d11[2]; t3[3] = (__bf16)d11[3];                  \
        *(bf16x4*)(pbase + ((16 + lr) * 28 + vb1) * 2) = t3;             \
    }                                                                    \
} while (0)

__global__ __launch_bounds__(128, 4)
void cconv_kernel(const float* __restrict__ feats,
                  const float* __restrict__ inpos,
                  const float* __restrict__ outpos,
                  const float* __restrict__ extents,
                  const float* __restrict__ importance,
                  const int*   __restrict__ nbrs,
                  const __bf16* __restrict__ wfrag,
                  const float* __restrict__ bias,
                  float* __restrict__ out)
{
    __shared__ __align__(16) unsigned char smem[LDS_BYTES];

    const int tid = threadIdx.x;
    const int blk = blockIdx.x;
    float* nrm = (float*)(smem + NRM_OFF);

    const float inv_r = 2.0f / extents[0];

    // ---------------- phase 0: weights (k-paired) ----------------
    {
        const int pt = tid >> 4;          // wave0 -> pts 0..3, wave1 -> 4..7
        const int kp = tid & 15;
        const int m  = blk * MB + pt;
        const int2 nn = *(const int2*)(nbrs + m * 32 + 2 * kp);
        const float ox = outpos[3 * m + 0];
        const float oy = outpos[3 * m + 1];
        const float oz = outpos[3 * m + 2];

        float cxA, cyA, czA, impA, cxB, cyB, czB, impB;
        {
            const int nb = nn.x;
            const float rx = (inpos[3 * nb + 0] - ox) * inv_r;
            const float ry = (inpos[3 * nb + 1] - oy) * inv_r;
            const float rz = (inpos[3 * nb + 2] - oz) * inv_r;
            const float dist = sqrtf(rx * rx + ry * ry + rz * rz);
            float imp = importance[nb];
            impA = (dist <= 1.0f) ? imp : 0.0f;
            const float linf = fmaxf(fabsf(rx), fmaxf(fabsf(ry), fabsf(rz)));
            const float sc = (linf > 1e-8f) ? (dist / linf) : 0.0f;
            cxA = fminf(fmaxf(rx * sc + 1.0f, 0.0f), 2.0f);
            cyA = fminf(fmaxf(ry * sc + 1.0f, 0.0f), 2.0f);
            czA = fminf(fmaxf(rz * sc + 1.0f, 0.0f), 2.0f);
        }
        {
            const int nb = nn.y;
            const float rx = (inpos[3 * nb + 0] - ox) * inv_r;
            const float ry = (inpos[3 * nb + 1] - oy) * inv_r;
            const float rz = (inpos[3 * nb + 2] - oz) * inv_r;
            const float dist = sqrtf(rx * rx + ry * ry + rz * rz);
            float imp = importance[nb];
            impB = (dist <= 1.0f) ? imp : 0.0f;
            const float linf = fmaxf(fabsf(rx), fmaxf(fabsf(ry), fabsf(rz)));
            const float sc = (linf > 1e-8f) ? (dist / linf) : 0.0f;
            cxB = fminf(fmaxf(rx * sc + 1.0f, 0.0f), 2.0f);
            cyB = fminf(fmaxf(ry * sc + 1.0f, 0.0f), 2.0f);
            czB = fminf(fmaxf(rz * sc + 1.0f, 0.0f), 2.0f);
        }

        float wxA[3], wyA[3], wzA[3], wxB[3], wyB[3], wzB[3];
        wxA[0] = fmaxf(0.f, 1.f - cxA) * impA;
        wxA[1] = (1.f - fabsf(cxA - 1.f)) * impA;
        wxA[2] = fmaxf(0.f, cxA - 1.f) * impA;
        wyA[0] = fmaxf(0.f, 1.f - cyA); wyA[1] = 1.f - fabsf(cyA - 1.f); wyA[2] = fmaxf(0.f, cyA - 1.f);
        wzA[0] = fmaxf(0.f, 1.f - czA); wzA[1] = 1.f - fabsf(czA - 1.f); wzA[2] = fmaxf(0.f, czA - 1.f);
        wxB[0] = fmaxf(0.f, 1.f - cxB) * impB;
        wxB[1] = (1.f - fabsf(cxB - 1.f)) * impB;
        wxB[2] = fmaxf(0.f, cxB - 1.f) * impB;
        wyB[0] = fmaxf(0.f, 1.f - cyB); wyB[1] = 1.f - fabsf(cyB - 1.f); wyB[2] = fmaxf(0.f, cyB - 1.f);
        wzB[0] = fmaxf(0.f, 1.f - czB); wzB[1] = 1.f - fabsf(czB - 1.f); wzB[2] = fmaxf(0.f, czB - 1.f);

        unsigned char* wrow = smem + pt * PT_STRIDE + kp * 4;
#pragma unroll
        for (int a = 0; a < 3; ++a)
#pragma unroll
            for (int b = 0; b < 3; ++b) {
                const float pA = wxA[a] * wyA[b];
                const float pB = wxB[a] * wyB[b];
#pragma unroll
                for (int c = 0; c < 3; ++c) {
                    const int v = a * 9 + b * 3 + c;
                    union { __bf16 h[2]; unsigned int u; } pk;
                    pk.h[0] = (__bf16)(pA * wzA[c]);    // k = 2kp
                    pk.h[1] = (__bf16)(pB * wzB[c]);    // k = 2kp+1
                    *(unsigned int*)(wrow + v * W_V) = pk.u;
                }
            }
        *(unsigned int*)(wrow + 27 * W_V) = 0u;          // pad voxel row

        float s = impA + impB;
        s += __shfl_xor(s, 1);
        s += __shfl_xor(s, 2);
        s += __shfl_xor(s, 4);
        s += __shfl_xor(s, 8);
        if (kp == 0) nrm[pt] = (s > 0.f) ? (1.f / fmaxf(s, 1e-12f)) : 0.f;
    }
    // NO barrier: each wave consumes exactly the w[pt] regions it wrote.

    // ---------------- phase 1: acc = w . f (pipelined gathers) ----------------
    const int wv   = tid >> 6;       // wave 0/1
    const int lane = tid & 63;
    const int grp  = lane >> 4;      // k-group
    const int lr   = lane & 15;
    const int k0   = grp * 8;
    const int* nb_base = nbrs + (blk * MB + wv * 4) * 32 + k0;

    float f0[16], f1[16];
    {
        const int4 nA0 = *(const int4*)(nb_base);
        const int4 nB0 = *(const int4*)(nb_base + 4);
        STAGE(f0, nA0, nB0);
        const int4 nA1 = *(const int4*)(nb_base + 32);
        const int4 nB1 = *(const int4*)(nb_base + 36);
        STAGE(f1, nA1, nB1);
        COMPUTE(0, f0);
        const int4 nA2 = *(const int4*)(nb_base + 64);
        const int4 nB2 = *(const int4*)(nb_base + 68);
        STAGE(f0, nA2, nB2);
        COMPUTE(1, f1);
        const int4 nA3 = *(const int4*)(nb_base + 96);
        const int4 nB3 = *(const int4*)(nb_base + 100);
        STAGE(f1, nA3, nB3);
        COMPUTE(2, f0);
        COMPUTE(3, f1);
    }
    __syncthreads();

    // ---------------- phase 2: out = acc . W (prefetched) ----------------
    const int nt0 = wv * 2, nt1 = wv * 2 + 1;
    const bf16x8* wb = (const bf16x8*)wfrag;
    const unsigned char* abase = smem + (lr & 7) * PT_STRIDE + grp * 16;

    f32x4 e0 = {0.f, 0.f, 0.f, 0.f}, e1 = {0.f, 0.f, 0.f, 0.f};
    bf16x8 w0c = wb[(nt0 * 28) * 64 + lane];
    bf16x8 w1c = wb[(nt1 * 28) * 64 + lane];
    bf16x8 ac  = *(const bf16x8*)(abase);
#pragma unroll
    for (int ks = 0; ks < 28; ++ks) {
        if (ks < 27) {
            const bf16x8 w0n = wb[(nt0 * 28 + ks + 1) * 64 + lane];
            const bf16x8 w1n = wb[(nt1 * 28 + ks + 1) * 64 + lane];
            const bf16x8 an  = *(const bf16x8*)(abase + (ks + 1) * 64);
            e0 = __builtin_amdgcn_mfma_f32_16x16x32_bf16(ac, w0c, e0, 0, 0, 0);
            e1 = __builtin_amdgcn_mfma_f32_16x16x32_bf16(ac, w1c, e1, 0, 0, 0);
            w0c = w0n; w1c = w1n; ac = an;
        } else {
            e0 = __builtin_amdgcn_mfma_f32_16x16x32_bf16(ac, w0c, e0, 0, 0, 0);
            e1 = __builtin_amdgcn_mfma_f32_16x16x32_bf16(ac, w1c, e1, 0, 0, 0);
        }
    }

    const int o0 = nt0 * 16 + lr;
    const int o1 = nt1 * 16 + lr;
    const float bb0 = bias[o0];
    const float bb1 = bias[o1];
    if (grp < 2) {
#pragma unroll
        for (int r = 0; r < 4; ++r) {
            const int pt = grp * 4 + r;      // D rows 8..15 are dups, skipped
            const float nv = nrm[pt];
            const int mg = blk * MB + pt;
            out[mg * 64 + o0] = e0[r] * nv + bb0;
            out[mg * 64 + o1] = e1[r] * nv + bb1;
        }
    }
}

extern "C" void kernel_launch(void* const* d_in, const int* in_sizes, int n_in,
                              void* d_out, int out_size, void* d_ws, size_t ws_size,
                              hipStream_t stream) {
    (void)in_sizes; (void)n_in; (void)out_size; (void)ws_size;
    const float* feats      = (const float*)d_in[0];
    const float* inpos      = (const float*)d_in[1];
    const float* outpos     = (const float*)d_in[2];
    const float* extents    = (const float*)d_in[3];
    const float* importance = (const float*)d_in[4];
    const int*   nbrs       = (const int*)d_in[5];
    const float* kern       = (const float*)d_in[6];
    const float* bias       = (const float*)d_in[7];
    float* outp = (float*)d_out;
    __bf16* wsb = (__bf16*)d_ws;          // 114688 B of scratch

    hipLaunchKernelGGL(wprep_kernel, dim3(224), dim3(256), 0, stream, kern, wsb);
    hipLaunchKernelGGL(cconv_kernel, dim3(NBLK), dim3(128), 0, stream,
                       feats, inpos, outpos, extents, importance,
                       nbrs, wsb, bias, outp);
}

// Round 4
// 189.667 us; speedup vs baseline: 5.5226x; 1.1114x over previous
//
#include <hip/hip_runtime.h>

// ContinuousConv: N=200000, M=100000, CIN=32, COUT=64, K=32, KS=3
// Round 4: MB=16 (4 waves), bf16 pre-converted features in d_ws (f32 fallback),
// channel-pair dword gathers (8 loads/pt), 4-deep staging, W prefetch depth 2.

typedef __attribute__((ext_vector_type(8))) __bf16 bf16x8;
typedef __attribute__((ext_vector_type(4))) __bf16 bf16x4;
typedef __attribute__((ext_vector_type(4))) float f32x4;
typedef unsigned int u32;
typedef unsigned short u16;

constexpr int NPTS = 200000;
constexpr int MPTS = 100000;
constexpr int MB   = 16;                  // points per block
constexpr int NBLK = MPTS / MB;           // 6250

// Per-pt LDS region, time-shared:
//   phase 0/1 read : w[v=0..27][k-slot] bf16, row stride 80 B (2240 B used)
//   phase 1 write  : acc[kk = ch*28+v] bf16, 1792 B (overwrites w after reads)
// PT_STRIDE=2256: 16-aligned; phase-2 row reads -> 2-way start-bank (free).
constexpr int PT_STRIDE = 2256;
constexpr int W_V       = 80;
constexpr int NRM_OFF   = MB * PT_STRIDE;        // 36096
constexpr int LDS_BYTES = NRM_OFF + 64 + 256;    // 36416 (covers spill reads to 36384)

// d_ws layout: Wfrag bf16 [4 nt][28 ks][64 lane][8] = 114688 B, then feats bf16 [N][32]
constexpr size_t WFRAG_ELEMS = 4 * 28 * 64 * 8;          // 57344
constexpr size_t FEATS_OFF_ELEMS = WFRAG_ELEMS;
constexpr size_t WS_NEED = (WFRAG_ELEMS + (size_t)NPTS * 32) * 2;   // ~12.9 MB

// ---- prep: Wfrag transform (blocks 0..223) + feats f32->bf16 (blocks 224..3348) ----
// Wfrag[nt][ks][lane][j] = W_bf16[ o = nt*16+(lane&15) ][ kk = ks*32 + (lane>>4)*8 + j ]
// with kk = ch*28 + v ; zero at pad v==27.
__global__ void prep_kernel(const float* __restrict__ kern,
                            const float* __restrict__ feats,
                            __bf16* __restrict__ wsb) {
    const int blk = blockIdx.x;
    if (blk < 224) {
        const int tid = blk * 256 + threadIdx.x;     // 0..57343 exactly
        const int j  = tid & 7;
        const int l  = (tid >> 3) & 63;
        const int s  = tid >> 9;
        const int ks = s % 28;
        const int nt = s / 28;
        const int kk = ks * 32 + ((l >> 4) << 3) + j;
        const int ch = kk / 28;
        const int v  = kk - ch * 28;
        const int o  = nt * 16 + (l & 15);
        const float val = (v < 27) ? kern[v * 2048 + ch * 64 + o] : 0.0f;
        wsb[tid] = (__bf16)val;
    } else {
        const int t = (blk - 224) * 256 + threadIdx.x;   // 0..799999 exactly
        const float4* src = (const float4*)feats + (size_t)t * 2;
        const float4 a = src[0];
        const float4 b = src[1];
        bf16x8 o;
        o[0]=(__bf16)a.x; o[1]=(__bf16)a.y; o[2]=(__bf16)a.z; o[3]=(__bf16)a.w;
        o[4]=(__bf16)b.x; o[5]=(__bf16)b.y; o[6]=(__bf16)b.z; o[7]=(__bf16)b.w;
        *(bf16x8*)(wsb + FEATS_OFF_ELEMS + (size_t)t * 8) = o;
    }
}

// stage 8 channel-pair dwords for one point's 8 neighbors
#define STAGE(q) do {                                                       \
    const int4 nA = *(const int4*)(nb_base + (q) * 32);                     \
    const int4 nB = *(const int4*)(nb_base + (q) * 32 + 4);                 \
    if constexpr (PRE) {                                                    \
        stq[q][0] = featsb[(size_t)nA.x * 16 + lr];                         \
        stq[q][1] = featsb[(size_t)nA.y * 16 + lr];                         \
        stq[q][2] = featsb[(size_t)nA.z * 16 + lr];                         \
        stq[q][3] = featsb[(size_t)nA.w * 16 + lr];                         \
        stq[q][4] = featsb[(size_t)nB.x * 16 + lr];                         \
        stq[q][5] = featsb[(size_t)nB.y * 16 + lr];                         \
        stq[q][6] = featsb[(size_t)nB.z * 16 + lr];                         \
        stq[q][7] = featsb[(size_t)nB.w * 16 + lr];                         \
    } else {                                                                \
        stf[q][0] = ((const float2*)(feats + (size_t)nA.x * 32))[lr];       \
        stf[q][1] = ((const float2*)(feats + (size_t)nA.y * 32))[lr];       \
        stf[q][2] = ((const float2*)(feats + (size_t)nA.z * 32))[lr];       \
        stf[q][3] = ((const float2*)(feats + (size_t)nA.w * 32))[lr];       \
        stf[q][4] = ((const float2*)(feats + (size_t)nB.x * 32))[lr];       \
        stf[q][5] = ((const float2*)(feats + (size_t)nB.y * 32))[lr];       \
        stf[q][6] = ((const float2*)(feats + (size_t)nB.z * 32))[lr];       \
        stf[q][7] = ((const float2*)(feats + (size_t)nB.w * 32))[lr];       \
    }                                                                       \
} while (0)

// one point's phase-1: b-frags (b0=even ch, b1=odd ch), 4 MFMAs, acc -> LDS
#define COMPUTE(q) do {                                                     \
    unsigned char* pbase = smem + (wv * 4 + (q)) * PT_STRIDE;               \
    bf16x8 b0, b1;                                                          \
    if constexpr (PRE) {                                                    \
        union { u16 u[8]; bf16x8 v; } B0, B1;                               \
        _Pragma("unroll")                                                   \
        for (int j = 0; j < 8; ++j) {                                       \
            B0.u[j] = (u16)(stq[q][j] & 0xffffu);                           \
            B1.u[j] = (u16)(stq[q][j] >> 16);                               \
        }                                                                   \
        b0 = B0.v; b1 = B1.v;                                               \
    } else {                                                                \
        _Pragma("unroll")                                                   \
        for (int j = 0; j < 8; ++j) {                                       \
            b0[j] = (__bf16)stf[q][j].x;                                    \
            b1[j] = (__bf16)stf[q][j].y;                                    \
        }                                                                   \
    }                                                                       \
    const bf16x8 a0 = *(const bf16x8*)(pbase + lr * W_V + k0 * 2);          \
    const bf16x8 a1 = *(const bf16x8*)(pbase + (16 + lr) * W_V + k0 * 2);   \
    f32x4 d00 = {0.f,0.f,0.f,0.f}, d01 = {0.f,0.f,0.f,0.f};                 \
    f32x4 d10 = {0.f,0.f,0.f,0.f}, d11 = {0.f,0.f,0.f,0.f};                 \
    d00 = __builtin_amdgcn_mfma_f32_16x16x32_bf16(a0, b0, d00, 0, 0, 0);    \
    d01 = __builtin_amdgcn_mfma_f32_16x16x32_bf16(a0, b1, d01, 0, 0, 0);    \
    d10 = __builtin_amdgcn_mfma_f32_16x16x32_bf16(a1, b0, d10, 0, 0, 0);    \
    d11 = __builtin_amdgcn_mfma_f32_16x16x32_bf16(a1, b1, d11, 0, 0, 0);    \
    const int vb0 = grp * 4, vb1 = 16 + grp * 4;                            \
    const int ch0 = 2 * lr, ch1 = 2 * lr + 1;                               \
    bf16x4 t0, t1;                                                          \
    t0[0]=(__bf16)d00[0]; t0[1]=(__bf16)d00[1];                             \
    t0[2]=(__bf16)d00[2]; t0[3]=(__bf16)d00[3];                             \
    *(bf16x4*)(pbase + (ch0 * 28 + vb0) * 2) = t0;                          \
    t1[0]=(__bf16)d01[0]; t1[1]=(__bf16)d01[1];                             \
    t1[2]=(__bf16)d01[2]; t1[3]=(__bf16)d01[3];                             \
    *(bf16x4*)(pbase + (ch1 * 28 + vb0) * 2) = t1;                          \
    if (vb1 < 28) {                                                         \
        bf16x4 t2, t3;                                                      \
        t2[0]=(__bf16)d10[0]; t2[1]=(__bf16)d10[1];                         \
        t2[2]=(__bf16)d10[2]; t2[3]=(__bf16)d10[3];                         \
        *(bf16x4*)(pbase + (ch0 * 28 + vb1) * 2) = t2;                      \
        t3[0]=(__bf16)d11[0]; t3[1]=(__bf16)d11[1];                         \
        t3[2]=(__bf16)d11[2]; t3[3]=(__bf16)d11[3];                         \
        *(bf16x4*)(pbase + (ch1 * 28 + vb1) * 2) = t3;                      \
    }                                                                       \
} while (0)

template<bool PRE>
__global__ __launch_bounds__(256, 4)
void cconv_kernel(const float* __restrict__ feats,
                  const u32* __restrict__ featsb,
                  const float* __restrict__ inpos,
                  const float* __restrict__ outpos,
                  const float* __restrict__ extents,
                  const float* __restrict__ importance,
                  const int*   __restrict__ nbrs,
                  const __bf16* __restrict__ wfrag,
                  const float* __restrict__ bias,
                  float* __restrict__ out)
{
    __shared__ __align__(16) unsigned char smem[LDS_BYTES];

    const int tid = threadIdx.x;
    const int blk = blockIdx.x;
    float* nrm = (float*)(smem + NRM_OFF);

    const float inv_r = 2.0f / extents[0];

    // ---------------- phase 0: weights (k-paired), wave-local pts ----------------
    {
        const int pt = tid >> 4;          // wave wv covers pts 4wv..4wv+3
        const int kp = tid & 15;
        const int m  = blk * MB + pt;
        const int2 nn = *(const int2*)(nbrs + m * 32 + 2 * kp);
        const float ox = outpos[3 * m + 0];
        const float oy = outpos[3 * m + 1];
        const float oz = outpos[3 * m + 2];

        float cxA, cyA, czA, impA, cxB, cyB, czB, impB;
        {
            const int nb = nn.x;
            const float rx = (inpos[3 * nb + 0] - ox) * inv_r;
            const float ry = (inpos[3 * nb + 1] - oy) * inv_r;
            const float rz = (inpos[3 * nb + 2] - oz) * inv_r;
            const float dist = sqrtf(rx * rx + ry * ry + rz * rz);
            float imp = importance[nb];
            impA = (dist <= 1.0f) ? imp : 0.0f;
            const float linf = fmaxf(fabsf(rx), fmaxf(fabsf(ry), fabsf(rz)));
            const float sc = (linf > 1e-8f) ? (dist / linf) : 0.0f;
            cxA = fminf(fmaxf(rx * sc + 1.0f, 0.0f), 2.0f);
            cyA = fminf(fmaxf(ry * sc + 1.0f, 0.0f), 2.0f);
            czA = fminf(fmaxf(rz * sc + 1.0f, 0.0f), 2.0f);
        }
        {
            const int nb = nn.y;
            const float rx = (inpos[3 * nb + 0] - ox) * inv_r;
            const float ry = (inpos[3 * nb + 1] - oy) * inv_r;
            const float rz = (inpos[3 * nb + 2] - oz) * inv_r;
            const float dist = sqrtf(rx * rx + ry * ry + rz * rz);
            float imp = importance[nb];
            impB = (dist <= 1.0f) ? imp : 0.0f;
            const float linf = fmaxf(fabsf(rx), fmaxf(fabsf(ry), fabsf(rz)));
            const float sc = (linf > 1e-8f) ? (dist / linf) : 0.0f;
            cxB = fminf(fmaxf(rx * sc + 1.0f, 0.0f), 2.0f);
            cyB = fminf(fmaxf(ry * sc + 1.0f, 0.0f), 2.0f);
            czB = fminf(fmaxf(rz * sc + 1.0f, 0.0f), 2.0f);
        }

        float wxA[3], wyA[3], wzA[3], wxB[3], wyB[3], wzB[3];
        wxA[0] = fmaxf(0.f, 1.f - cxA) * impA;
        wxA[1] = (1.f - fabsf(cxA - 1.f)) * impA;
        wxA[2] = fmaxf(0.f, cxA - 1.f) * impA;
        wyA[0] = fmaxf(0.f, 1.f - cyA); wyA[1] = 1.f - fabsf(cyA - 1.f); wyA[2] = fmaxf(0.f, cyA - 1.f);
        wzA[0] = fmaxf(0.f, 1.f - czA); wzA[1] = 1.f - fabsf(czA - 1.f); wzA[2] = fmaxf(0.f, czA - 1.f);
        wxB[0] = fmaxf(0.f, 1.f - cxB) * impB;
        wxB[1] = (1.f - fabsf(cxB - 1.f)) * impB;
        wxB[2] = fmaxf(0.f, cxB - 1.f) * impB;
        wyB[0] = fmaxf(0.f, 1.f - cyB); wyB[1] = 1.f - fabsf(cyB - 1.f); wyB[2] = fmaxf(0.f, cyB - 1.f);
        wzB[0] = fmaxf(0.f, 1.f - czB); wzB[1] = 1.f - fabsf(czB - 1.f); wzB[2] = fmaxf(0.f, czB - 1.f);

        unsigned char* wrow = smem + pt * PT_STRIDE + kp * 4;
#pragma unroll
        for (int a = 0; a < 3; ++a)
#pragma unroll
            for (int b = 0; b < 3; ++b) {
                const float pA = wxA[a] * wyA[b];
                const float pB = wxB[a] * wyB[b];
#pragma unroll
                for (int c = 0; c < 3; ++c) {
                    const int v = a * 9 + b * 3 + c;
                    union { __bf16 h[2]; u32 u; } pk;
                    pk.h[0] = (__bf16)(pA * wzA[c]);    // k = 2kp
                    pk.h[1] = (__bf16)(pB * wzB[c]);    // k = 2kp+1
                    *(u32*)(wrow + v * W_V) = pk.u;
                }
            }
        *(u32*)(wrow + 27 * W_V) = 0u;                   // pad voxel row

        float s = impA + impB;
        s += __shfl_xor(s, 1);
        s += __shfl_xor(s, 2);
        s += __shfl_xor(s, 4);
        s += __shfl_xor(s, 8);
        if (kp == 0) nrm[pt] = (s > 0.f) ? (1.f / fmaxf(s, 1e-12f)) : 0.f;
    }
    // NO barrier: each wave consumes exactly the w[pt] regions it wrote.

    // ---------------- phase 1: acc = w . f (4-deep staged gathers) ----------------
    const int wv   = tid >> 6;       // wave 0..3
    const int lane = tid & 63;
    const int grp  = lane >> 4;      // k-group
    const int lr   = lane & 15;
    const int k0   = grp * 8;
    const int* nb_base = nbrs + (blk * MB + wv * 4) * 32 + k0;

    u32    stq[4][8];
    float2 stf[4][8];
    STAGE(0); STAGE(1); STAGE(2); STAGE(3);
    COMPUTE(0); COMPUTE(1); COMPUTE(2); COMPUTE(3);

    // ---------------- phase 2: out = acc . W (W prefetch depth 2) ----------------
    const bf16x8* wb = (const bf16x8*)wfrag;
    bf16x8 w0 = wb[(size_t)(wv * 28 + 0) * 64 + lane];
    bf16x8 w1 = wb[(size_t)(wv * 28 + 1) * 64 + lane];
    __syncthreads();

    const unsigned char* abase = smem + lr * PT_STRIDE + grp * 16;
    f32x4 e = {0.f, 0.f, 0.f, 0.f};
    bf16x8 a = *(const bf16x8*)(abase);
#pragma unroll
    for (int ks = 0; ks < 28; ++ks) {
        bf16x8 wn, an;
        if (ks < 26) wn = wb[(size_t)(wv * 28 + ks + 2) * 64 + lane];
        if (ks < 27) an = *(const bf16x8*)(abase + (ks + 1) * 64);
        e = __builtin_amdgcn_mfma_f32_16x16x32_bf16(a, w0, e, 0, 0, 0);
        w0 = w1;
        if (ks < 26) w1 = wn;
        if (ks < 27) a = an;
    }

    const int o  = wv * 16 + lr;
    const float bb = bias[o];
#pragma unroll
    for (int r = 0; r < 4; ++r) {
        const int pt = grp * 4 + r;                 // D row = pt, all 16 used
        out[(size_t)(blk * MB + pt) * 64 + o] = e[r] * nrm[pt] + bb;
    }
}

extern "C" void kernel_launch(void* const* d_in, const int* in_sizes, int n_in,
                              void* d_out, int out_size, void* d_ws, size_t ws_size,
                              hipStream_t stream) {
    (void)in_sizes; (void)n_in; (void)out_size;
    const float* feats      = (const float*)d_in[0];
    const float* inpos      = (const float*)d_in[1];
    const float* outpos     = (const float*)d_in[2];
    const float* extents    = (const float*)d_in[3];
    const float* importance = (const float*)d_in[4];
    const int*   nbrs       = (const int*)d_in[5];
    const float* kern       = (const float*)d_in[6];
    const float* bias       = (const float*)d_in[7];
    float* outp = (float*)d_out;
    __bf16* wsb = (__bf16*)d_ws;

    const bool pre = ws_size >= WS_NEED;   // constant per process -> same graph every call

    hipLaunchKernelGGL(prep_kernel, dim3(pre ? 3349 : 224), dim3(256), 0, stream,
                       kern, feats, wsb);
    if (pre) {
        hipLaunchKernelGGL(cconv_kernel<true>, dim3(NBLK), dim3(256), 0, stream,
                           feats, (const u32*)(wsb + FEATS_OFF_ELEMS), inpos, outpos,
                           extents, importance, nbrs, wsb, bias, outp);
    } else {
        hipLaunchKernelGGL(cconv_kernel<false>, dim3(NBLK), dim3(256), 0, stream,
                           feats, (const u32*)(wsb + FEATS_OFF_ELEMS), inpos, outpos,
                           extents, importance, nbrs, wsb, bias, outp);
    }
}